// Round 11
// baseline (853.212 us; speedup 1.0000x reference)
//
#include <hip/hip_runtime.h>
#include <hip/hip_bf16.h>

// MHRetention (B=4, L=4096, EMB=2048, H=16, hd=128), fp32 in/out, bf16 MFMA compute.
// gemm256: 256x256, BK=64, 8 waves, 128 KiB dbuf LDS, counted-vmcnt schedule
// (skeleton verified rounds 6/9), now using v_mfma_f32_32x32x16_bf16:
// 4 phases per 2 K-tiles, 16 MFMA32 per phase, same staging/vmcnt/barrier points.
// gemmO: fused SRMS-norm*U epilogue. gemmKV/kv_reduce/cvt unchanged (verified).

typedef unsigned int u32;
typedef unsigned short u16;
typedef __bf16 bf16x8 __attribute__((ext_vector_type(8)));
typedef float f32x4 __attribute__((ext_vector_type(4)));
typedef float f32x16 __attribute__((ext_vector_type(16)));

__device__ __forceinline__ u16 f2bf(float f) {
  u32 u = __float_as_uint(f);
  u = (u + 0x7fffu + ((u >> 16) & 1u)) >> 16;
  return (u16)u;
}
__device__ __forceinline__ float bf2f(u16 s) { return __uint_as_float(((u32)s) << 16); }

__device__ __forceinline__ void gl_lds16(const void* g, void* l) {
  __builtin_amdgcn_global_load_lds((const __attribute__((address_space(1))) void*)g,
                                   (__attribute__((address_space(3))) void*)l, 16, 0, 0);
}

__device__ __forceinline__ void bar() {
  asm volatile("" ::: "memory");
  __builtin_amdgcn_s_barrier();
  asm volatile("" ::: "memory");
}

#define INV_SCALE 0.08838834764831845f  // 1/sqrt(128)

// ---------------- fp32 -> bf16 conversion ----------------
__global__ __launch_bounds__(256) void cvt_f32_bf16(const float4* __restrict__ in,
                                                    u16* __restrict__ out, int n4) {
  int i = blockIdx.x * 256 + threadIdx.x;
  int stride = gridDim.x * 256;
  for (; i < n4; i += stride) {
    float4 v = in[i];
    u32 lo = (u32)f2bf(v.x) | ((u32)f2bf(v.y) << 16);
    u32 hi = (u32)f2bf(v.z) | ((u32)f2bf(v.w) << 16);
    ((uint2*)out)[i] = make_uint2(lo, hi);
  }
}

// ================= 256x256 big GEMM (M=16384, N=2048, K=2048) =================
// C[m][n] = sum_k A[m][k]*B[n][k]; MODE: 0=Q,1=KT,2=VT,3=U,6=final fp32
template <int MODE>
__global__ __launch_bounds__(512, 2) void gemm256(const u16* __restrict__ Ab,
                                                  const u16* __restrict__ Bb,
                                                  void* __restrict__ Cb) {
  __shared__ __align__(16) char smem[131072];

  const int t = threadIdx.x;
  const int u = t & 63;
  const int wid = t >> 6;          // 0..7
  const int wm = wid >> 2;         // 0..1 (M half)
  const int wn = wid & 3;          // 0..3 (N quarter)

  // XCD-bijective swizzle: 512 blocks, 512 % 8 == 0
  const int wgid = blockIdx.x;
  const int swz = (wgid & 7) * 64 + (wgid >> 3);
  const int mt = swz >> 3;         // 0..63
  const int nt = swz & 7;          // 0..7

  const u16* Asrc = Ab + (size_t)mt * 256 * 2048;
  const u16* Bsrc = Bb + (size_t)nt * 256 * 2048;

  const int srow = t >> 3;                         // 0..63
  const int scol = ((t & 7) ^ (srow & 7)) * 8;     // source col pre-swizzle (involution)

  // 32x32x16 fragment reads: row = (u&31), k = ks*16 + (u>>5)*8
  const int ard = wm * 16384;
  const int brd = 32768 + (wn >> 1) * 16384;
  const int arow32 = (u & 31) * 128;                      // + mi*4096 bytes
  const int brow32 = ((wn & 1) * 64 + (u & 31)) * 128;    // + ni*4096 bytes
  const int cs0 = ((0 + (u >> 5)) ^ (u & 7)) * 16;        // ks=0 granule
  const int cs1 = ((2 + (u >> 5)) ^ (u & 7)) * 16;        // ks=1
  const int cs2 = ((4 + (u >> 5)) ^ (u & 7)) * 16;        // ks=2
  const int cs3 = ((6 + (u >> 5)) ^ (u & 7)) * 16;        // ks=3

#define STG(base, R, kb, reg)                                                            \
  {                                                                                      \
    gl_lds16((base) + (size_t)((R) + srow) * 2048 + (kb) + scol, smem + (reg) + t * 16); \
    gl_lds16((base) + (size_t)((R) + 64 + srow) * 2048 + (kb) + scol,                    \
             smem + (reg) + 8192 + t * 16);                                              \
  }

#define LDA32(buf, mi, cs) (*(const bf16x8*)(smem + (buf) + ard + (mi) * 4096 + arow32 + (cs)))
#define LDB32(buf, ni, cs) (*(const bf16x8*)(smem + (buf) + brd + (ni) * 4096 + brow32 + (cs)))
#define MF32(d, a_, b_) d = __builtin_amdgcn_mfma_f32_32x32x16_bf16(a_, b_, d, 0, 0, 0)
// 16 MFMA32: (2 mi) x (2 ni) x 4 ks, ks-major for dep distance 4
#define PH32(A0, A1, B0, B1)                                              \
  MF32(A0, a00, b00); MF32(A1, a00, b10); MF32(B0, a10, b00); MF32(B1, a10, b10); \
  MF32(A0, a01, b01); MF32(A1, a01, b11); MF32(B0, a11, b01); MF32(B1, a11, b11); \
  MF32(A0, a02, b02); MF32(A1, a02, b12); MF32(B0, a12, b02); MF32(B1, a12, b12); \
  MF32(A0, a03, b03); MF32(A1, a03, b13); MF32(B0, a13, b03); MF32(B1, a13, b13);

  f32x16 acc[4][2];
#pragma unroll
  for (int i = 0; i < 4; ++i)
#pragma unroll
    for (int j = 0; j < 2; ++j)
#pragma unroll
      for (int e = 0; e < 16; ++e) acc[i][j][e] = 0.f;

  bf16x8 a00, a01, a02, a03, a10, a11, a12, a13;
  bf16x8 b00, b01, b02, b03, b10, b11, b12, b13;

  // prologue: tile0 all halves + tile1 B halves (12 loads); vmcnt(4) -> tile0 landed
  STG(Bsrc, 0, 0, 32768) STG(Bsrc, 128, 0, 49152)
  STG(Asrc, 0, 0, 0) STG(Asrc, 128, 0, 16384)
  STG(Bsrc, 0, 64, 65536 + 32768) STG(Bsrc, 128, 64, 65536 + 49152)
  asm volatile("s_waitcnt vmcnt(4)" ::: "memory");
  bar();

  for (int i = 0; i < 16; ++i) {
    const int kA1 = (2 * i + 1) * 64;
    const int kT2 = (2 * i + 2) * 64;
    const int kB3 = (2 * i + 3) * 64;
    // ---- P1: buf0 B(all) + A(mi0,1); stage A(2i+1)->buf1 ----
    b00 = LDB32(0, 0, cs0); b01 = LDB32(0, 0, cs1); b02 = LDB32(0, 0, cs2); b03 = LDB32(0, 0, cs3);
    b10 = LDB32(0, 1, cs0); b11 = LDB32(0, 1, cs1); b12 = LDB32(0, 1, cs2); b13 = LDB32(0, 1, cs3);
    a00 = LDA32(0, 0, cs0); a01 = LDA32(0, 0, cs1); a02 = LDA32(0, 0, cs2); a03 = LDA32(0, 0, cs3);
    a10 = LDA32(0, 1, cs0); a11 = LDA32(0, 1, cs1); a12 = LDA32(0, 1, cs2); a13 = LDA32(0, 1, cs3);
    STG(Asrc, 0, kA1, 65536 + 0) STG(Asrc, 128, kA1, 65536 + 16384)
    bar();
    __builtin_amdgcn_s_setprio(1);
    PH32(acc[0][0], acc[0][1], acc[1][0], acc[1][1])
    __builtin_amdgcn_s_setprio(0);
    bar();
    // ---- P2: buf0 A(mi2,3); stage B(2i+2)->buf0; vmcnt publishes tile 2i+1 ----
    a00 = LDA32(0, 2, cs0); a01 = LDA32(0, 2, cs1); a02 = LDA32(0, 2, cs2); a03 = LDA32(0, 2, cs3);
    a10 = LDA32(0, 3, cs0); a11 = LDA32(0, 3, cs1); a12 = LDA32(0, 3, cs2); a13 = LDA32(0, 3, cs3);
    if (i < 15) { STG(Bsrc, 0, kT2, 32768) STG(Bsrc, 128, kT2, 49152) }
    bar();
    __builtin_amdgcn_s_setprio(1);
    PH32(acc[2][0], acc[2][1], acc[3][0], acc[3][1])
    __builtin_amdgcn_s_setprio(0);
    if (i == 15) { asm volatile("s_waitcnt vmcnt(0)" ::: "memory"); }
    else         { asm volatile("s_waitcnt vmcnt(4)" ::: "memory"); }
    bar();
    // ---- P3: buf1 B(all) + A(mi0,1); stage A(2i+2)->buf0 ----
    b00 = LDB32(65536, 0, cs0); b01 = LDB32(65536, 0, cs1); b02 = LDB32(65536, 0, cs2); b03 = LDB32(65536, 0, cs3);
    b10 = LDB32(65536, 1, cs0); b11 = LDB32(65536, 1, cs1); b12 = LDB32(65536, 1, cs2); b13 = LDB32(65536, 1, cs3);
    a00 = LDA32(65536, 0, cs0); a01 = LDA32(65536, 0, cs1); a02 = LDA32(65536, 0, cs2); a03 = LDA32(65536, 0, cs3);
    a10 = LDA32(65536, 1, cs0); a11 = LDA32(65536, 1, cs1); a12 = LDA32(65536, 1, cs2); a13 = LDA32(65536, 1, cs3);
    if (i < 15) { STG(Asrc, 0, kT2, 0) STG(Asrc, 128, kT2, 16384) }
    bar();
    __builtin_amdgcn_s_setprio(1);
    PH32(acc[0][0], acc[0][1], acc[1][0], acc[1][1])
    __builtin_amdgcn_s_setprio(0);
    bar();
    // ---- P4: buf1 A(mi2,3); stage B(2i+3)->buf1; vmcnt publishes tile 2i+2 ----
    a00 = LDA32(65536, 2, cs0); a01 = LDA32(65536, 2, cs1); a02 = LDA32(65536, 2, cs2); a03 = LDA32(65536, 2, cs3);
    a10 = LDA32(65536, 3, cs0); a11 = LDA32(65536, 3, cs1); a12 = LDA32(65536, 3, cs2); a13 = LDA32(65536, 3, cs3);
    if (i < 15) { STG(Bsrc, 0, kB3, 65536 + 32768) STG(Bsrc, 128, kB3, 65536 + 49152) }
    bar();
    __builtin_amdgcn_s_setprio(1);
    PH32(acc[2][0], acc[2][1], acc[3][0], acc[3][1])
    __builtin_amdgcn_s_setprio(0);
    if (i == 15) { asm volatile("s_waitcnt vmcnt(0)" ::: "memory"); }
    else         { asm volatile("s_waitcnt vmcnt(4)" ::: "memory"); }
    bar();
  }
#undef PH32
#undef MF32
#undef LDA32
#undef LDB32
#undef STG

  // epilogue (scatter, round-6-proven pattern; 32x32 C/D mapping m74/m101):
  // m = mbase + mi*32 + (r&3) + 8*(r>>2) + 4*(u>>5); n = nbase + ni*32 + (u&31)
  const int mbase = mt * 256 + wm * 128;
  const int nbase = nt * 256 + wn * 64;
#pragma unroll
  for (int mi = 0; mi < 4; ++mi)
#pragma unroll
    for (int ni = 0; ni < 2; ++ni)
#pragma unroll
      for (int r = 0; r < 16; ++r) {
        float v = acc[mi][ni][r];
        int m = mbase + mi * 32 + (r & 3) + ((r >> 2) << 3) + ((u >> 5) << 2);
        int n = nbase + ni * 32 + (u & 31);
        if constexpr (MODE == 0) {  // Q
          ((u16*)Cb)[(size_t)m * 2048 + n] = f2bf(fmaxf(v, 0.f) * INV_SCALE);
        } else if constexpr (MODE == 1 || MODE == 2) {  // KT / VT per-head transposed
          float q = (MODE == 1) ? fmaxf(v, 0.f) * INV_SCALE : v;
          int bh = ((m >> 12) << 4) | (n >> 7);
          ((u16*)Cb)[(size_t)bh * 524288 + (size_t)(n & 127) * 4096 + (m & 4095)] = f2bf(q);
        } else if constexpr (MODE == 3) {  // U = silu
          float s = v * (1.f / (1.f + __expf(-v)));
          ((u16*)Cb)[(size_t)m * 2048 + n] = f2bf(s);
        } else {  // MODE 6: final fp32
          ((float*)Cb)[(size_t)m * 2048 + n] = v;
        }
      }
}

// ================= 128x128 KV-partial kernel =================
__global__ __launch_bounds__(256) void gemmKV(const u16* __restrict__ Ab,
                                              const u16* __restrict__ Bb,
                                              float* __restrict__ Cb) {
  __shared__ __align__(16) char smem[16384];

  const int t = threadIdx.x;
  const int u = t & 63;
  const int wid = t >> 6;
  const int wr = wid >> 1, wc = wid & 1;

  const u16* Au = Ab + (size_t)blockIdx.y * 524288 + blockIdx.x * 1024;
  const u16* Bu = Bb + (size_t)blockIdx.y * 524288 + blockIdx.x * 1024;

  const int srow = t >> 2;
  const int scolb = (t & 3) * 16;

  f32x4 acc[4][4];
#pragma unroll
  for (int i = 0; i < 4; ++i)
#pragma unroll
    for (int j = 0; j < 4; ++j) acc[i][j] = (f32x4){0.f, 0.f, 0.f, 0.f};

  const int aoff = (wr * 64 + (u & 15)) * 64 + (u >> 4) * 16;
  const int boff = 8192 + (wc * 64 + (u & 15)) * 64 + (u >> 4) * 16;

  for (int k0 = 0; k0 < 1024; k0 += 32) {
    const char* ga = (const char*)Au + ((size_t)srow * 4096 + k0) * 2 + scolb;
    const char* gb = (const char*)Bu + ((size_t)srow * 4096 + k0) * 2 + scolb;
    gl_lds16(ga, smem + t * 16);
    gl_lds16(ga + (size_t)64 * 4096 * 2, smem + 4096 + t * 16);
    gl_lds16(gb, smem + 8192 + t * 16);
    gl_lds16(gb + (size_t)64 * 4096 * 2, smem + 12288 + t * 16);
    __syncthreads();

    bf16x8 af[4], bfr[4];
#pragma unroll
    for (int mi = 0; mi < 4; ++mi) af[mi] = *(const bf16x8*)(smem + aoff + mi * 1024);
#pragma unroll
    for (int ni = 0; ni < 4; ++ni) bfr[ni] = *(const bf16x8*)(smem + boff + ni * 1024);
#pragma unroll
    for (int mi = 0; mi < 4; ++mi)
#pragma unroll
      for (int ni = 0; ni < 4; ++ni)
        acc[mi][ni] = __builtin_amdgcn_mfma_f32_16x16x32_bf16(af[mi], bfr[ni], acc[mi][ni], 0, 0, 0);
    __syncthreads();
  }

#pragma unroll
  for (int mi = 0; mi < 4; ++mi)
#pragma unroll
    for (int ni = 0; ni < 4; ++ni)
#pragma unroll
      for (int j = 0; j < 4; ++j) {
        int ml = wr * 64 + mi * 16 + ((u >> 4) << 2) + j;
        int nl = wc * 64 + ni * 16 + (u & 15);
        Cb[((size_t)blockIdx.x * 64 + blockIdx.y) * 16384 + ml * 128 + nl] = acc[mi][ni][j];
      }
}

// ---------------- KV partial reduce: 4 chunks fp32 -> bf16 ----------------
__global__ __launch_bounds__(256) void kv_reduce(const float* __restrict__ part,
                                                 u16* __restrict__ kvt) {
  int i = blockIdx.x * 256 + threadIdx.x;  // 64*128*128 = 1048576 elements
  float s = part[i] + part[i + 1048576] + part[i + 2097152] + part[i + 3145728];
  kvt[i] = f2bf(s);
}

// ======= gemmO: O = Q @ KVT^T per head, fused SRMS-norm * U epilogue =======
__global__ __launch_bounds__(256) void gemmO(const u16* __restrict__ Qb,
                                             const u16* __restrict__ KVT,
                                             const u16* __restrict__ Ub,
                                             u16* __restrict__ Ob) {
  __shared__ __align__(16) char smem[16384];
  __shared__ float ssb[2][128];

  const int t = threadIdx.x;
  const int u = t & 63;
  const int wid = t >> 6;
  const int wr = wid >> 1, wc = wid & 1;

  const int bh = blockIdx.y, b = bh >> 4, h = bh & 15;
  const int rowbase = b * 4096 + blockIdx.x * 128;
  const u16* Au = Qb + (size_t)rowbase * 2048 + h * 128;
  const u16* Bu = KVT + (size_t)bh * 16384;

  const int srow = t >> 2;
  const int scolb = (t & 3) * 16;

  f32x4 acc[4][4];
#pragma unroll
  for (int i = 0; i < 4; ++i)
#pragma unroll
    for (int j = 0; j < 4; ++j) acc[i][j] = (f32x4){0.f, 0.f, 0.f, 0.f};

  const int aoff = (wr * 64 + (u & 15)) * 64 + (u >> 4) * 16;
  const int boff = 8192 + (wc * 64 + (u & 15)) * 64 + (u >> 4) * 16;

  for (int k0 = 0; k0 < 128; k0 += 32) {
    const char* ga = (const char*)Au + ((size_t)srow * 2048 + k0) * 2 + scolb;
    const char* gb = (const char*)Bu + ((size_t)srow * 128 + k0) * 2 + scolb;
    gl_lds16(ga, smem + t * 16);
    gl_lds16(ga + (size_t)64 * 2048 * 2, smem + 4096 + t * 16);
    gl_lds16(gb, smem + 8192 + t * 16);
    gl_lds16(gb + (size_t)64 * 128 * 2, smem + 12288 + t * 16);
    __syncthreads();

    bf16x8 af[4], bfr[4];
#pragma unroll
    for (int mi = 0; mi < 4; ++mi) af[mi] = *(const bf16x8*)(smem + aoff + mi * 1024);
#pragma unroll
    for (int ni = 0; ni < 4; ++ni) bfr[ni] = *(const bf16x8*)(smem + boff + ni * 1024);
#pragma unroll
    for (int mi = 0; mi < 4; ++mi)
#pragma unroll
      for (int ni = 0; ni < 4; ++ni)
        acc[mi][ni] = __builtin_amdgcn_mfma_f32_16x16x32_bf16(af[mi], bfr[ni], acc[mi][ni], 0, 0, 0);
    __syncthreads();
  }

  // row ssq: reduce 4 ni + 16 lanes (u&15 group)
#pragma unroll
  for (int mi = 0; mi < 4; ++mi)
#pragma unroll
    for (int j = 0; j < 4; ++j) {
      float s = acc[mi][0][j] * acc[mi][0][j] + acc[mi][1][j] * acc[mi][1][j] +
                acc[mi][2][j] * acc[mi][2][j] + acc[mi][3][j] * acc[mi][3][j];
      s += __shfl_xor(s, 1); s += __shfl_xor(s, 2);
      s += __shfl_xor(s, 4); s += __shfl_xor(s, 8);
      if ((u & 15) == 0) ssb[wc][wr * 64 + mi * 16 + ((u >> 4) << 2) + j] = s;
    }
  __syncthreads();

#pragma unroll
  for (int mi = 0; mi < 4; ++mi)
#pragma unroll
    for (int j = 0; j < 4; ++j) {
      int ml = wr * 64 + mi * 16 + ((u >> 4) << 2) + j;
      float ss = ssb[0][ml] + ssb[1][ml];
      float inv = 1.0f / fmaxf(sqrtf(ss * (1.0f / 128.0f)), 1e-12f);
      size_t rb = (size_t)(rowbase + ml) * 2048 + h * 128;
#pragma unroll
      for (int ni = 0; ni < 4; ++ni) {
        int nl = wc * 64 + ni * 16 + (u & 15);
        float uval = bf2f(Ub[rb + nl]);
        Ob[rb + nl] = f2bf(acc[mi][ni][j] * inv * uval);
      }
    }
}

extern "C" void kernel_launch(void* const* d_in, const int* in_sizes, int n_in,
                              void* d_out, int out_size, void* d_ws, size_t ws_size,
                              hipStream_t stream) {
  (void)in_sizes; (void)n_in; (void)out_size; (void)ws_size;
  const float* x  = (const float*)d_in[0];
  const float* wq = (const float*)d_in[1];
  const float* wk = (const float*)d_in[2];
  const float* wv = (const float*)d_in[3];
  const float* wu = (const float*)d_in[4];
  const float* wo = (const float*)d_in[5];

  char* ws = (char*)d_ws;
  u16* wb   = (u16*)(ws + 0);             // 8 MiB, reused for each weight
  u16* xb   = (u16*)(ws + 8388608);       // 64 MiB (reused as Ob later)
  u16* Qb   = (u16*)(ws + 75497472);      // 64 MiB
  u16* Ub   = (u16*)(ws + 142606336);     // 64 MiB
  float* KVp = (float*)(ws + 209715200);  // 16 MiB: 4x64x128x128 fp32
  u16* KVT  = (u16*)(ws + 226492416);     // 2 MiB (end: 228,589,568 B)
  u16* Ob   = xb;                         // alias: xb dead after projections
  u16* KT   = (u16*)d_out;                // d_out scratch (first 64 MiB)
  u16* VT   = (u16*)d_out + 33554432;     // d_out scratch (second 64 MiB)

  // x -> bf16
  cvt_f32_bf16<<<4096, 256, 0, stream>>>((const float4*)x, xb, 8388608);

  // Q
  cvt_f32_bf16<<<4096, 256, 0, stream>>>((const float4*)wq, wb, 1048576);
  gemm256<0><<<512, 512, 0, stream>>>(xb, wb, Qb);
  // K -> KT
  cvt_f32_bf16<<<4096, 256, 0, stream>>>((const float4*)wk, wb, 1048576);
  gemm256<1><<<512, 512, 0, stream>>>(xb, wb, KT);
  // V -> VT
  cvt_f32_bf16<<<4096, 256, 0, stream>>>((const float4*)wv, wb, 1048576);
  gemm256<2><<<512, 512, 0, stream>>>(xb, wb, VT);
  // U
  cvt_f32_bf16<<<4096, 256, 0, stream>>>((const float4*)wu, wb, 1048576);
  gemm256<3><<<512, 512, 0, stream>>>(xb, wb, Ub);

  // KVT[bh][e][d] = sum_l VT[e][l] * KT[d][l]
  gemmKV<<<dim3(4, 64), 256, 0, stream>>>(VT, KT, KVp);
  kv_reduce<<<4096, 256, 0, stream>>>(KVp, KVT);

  // O = Q @ KVT^T per head, fused SRMS*U -> Ob (= xb). KT/VT dead after this.
  gemmO<<<dim3(32, 64), 256, 0, stream>>>(Qb, KVT, Ub, Ob);

  // out = Ob @ wo^T (fp32, full overwrite of d_out)
  cvt_f32_bf16<<<4096, 256, 0, stream>>>((const float4*)wo, wb, 1048576);
  gemm256<6><<<512, 512, 0, stream>>>(Ob, wb, (float*)d_out);
}

// Round 12
// 759.138 us; speedup vs baseline: 1.1239x; 1.1239x over previous
//
#include <hip/hip_runtime.h>
#include <hip/hip_bf16.h>

// MHRetention (B=4, L=4096, EMB=2048, H=16, hd=128), fp32 in/out, bf16 MFMA compute.
// gemm256 (modes 0,1,2,3,6): round-6/9-verified 256x256 BK=64 8-phase counted-vmcnt
// kernel (16x16x32 MFMA) with scatter epilogue. Round-11's 32x32x16 variant regressed
// (1.26e7 bank conflicts, MfmaUtil 45->38.6) and was reverted.
// gemmO: O = Q@KVT with fused SRMS-norm*U epilogue (verified round 8/9).

typedef unsigned int u32;
typedef unsigned short u16;
typedef __bf16 bf16x8 __attribute__((ext_vector_type(8)));
typedef float f32x4 __attribute__((ext_vector_type(4)));

__device__ __forceinline__ u16 f2bf(float f) {
  u32 u = __float_as_uint(f);
  u = (u + 0x7fffu + ((u >> 16) & 1u)) >> 16;
  return (u16)u;
}
__device__ __forceinline__ float bf2f(u16 s) { return __uint_as_float(((u32)s) << 16); }

__device__ __forceinline__ void gl_lds16(const void* g, void* l) {
  __builtin_amdgcn_global_load_lds((const __attribute__((address_space(1))) void*)g,
                                   (__attribute__((address_space(3))) void*)l, 16, 0, 0);
}

__device__ __forceinline__ void bar() {
  asm volatile("" ::: "memory");
  __builtin_amdgcn_s_barrier();
  asm volatile("" ::: "memory");
}

#define INV_SCALE 0.08838834764831845f  // 1/sqrt(128)

// ---------------- fp32 -> bf16 conversion ----------------
__global__ __launch_bounds__(256) void cvt_f32_bf16(const float4* __restrict__ in,
                                                    u16* __restrict__ out, int n4) {
  int i = blockIdx.x * 256 + threadIdx.x;
  int stride = gridDim.x * 256;
  for (; i < n4; i += stride) {
    float4 v = in[i];
    u32 lo = (u32)f2bf(v.x) | ((u32)f2bf(v.y) << 16);
    u32 hi = (u32)f2bf(v.z) | ((u32)f2bf(v.w) << 16);
    ((uint2*)out)[i] = make_uint2(lo, hi);
  }
}

// ================= 256x256 big GEMM (M=16384, N=2048, K=2048) =================
// C[m][n] = sum_k A[m][k]*B[n][k]; MODE: 0=Q,1=KT,2=VT,3=U,6=final fp32
// Round-6/9-verified kernel (K-loop + scatter epilogue).
template <int MODE>
__global__ __launch_bounds__(512, 2) void gemm256(const u16* __restrict__ Ab,
                                                  const u16* __restrict__ Bb,
                                                  void* __restrict__ Cb) {
  __shared__ __align__(16) char smem[131072];

  const int t = threadIdx.x;
  const int u = t & 63;
  const int wid = t >> 6;          // 0..7
  const int wm = wid >> 2;         // 0..1 (M half)
  const int wn = wid & 3;          // 0..3 (N quarter)

  // XCD-bijective swizzle: 512 blocks, 512 % 8 == 0
  const int wgid = blockIdx.x;
  const int swz = (wgid & 7) * 64 + (wgid >> 3);
  const int mt = swz >> 3;         // 0..63
  const int nt = swz & 7;          // 0..7

  const u16* Asrc = Ab + (size_t)mt * 256 * 2048;
  const u16* Bsrc = Bb + (size_t)nt * 256 * 2048;

  const int srow = t >> 3;                         // 0..63
  const int scol = ((t & 7) ^ (srow & 7)) * 8;     // element col offset (involution)

  const int ard = wm * 16384;
  const int brd = 32768 + (wn >> 1) * 16384;
  const int arow = (u & 15) * 128;                       // + mi*2048 bytes
  const int brow = ((wn & 1) * 64 + (u & 15)) * 128;     // + ni*2048 bytes
  const int cr0 = ((u >> 4) ^ (u & 7)) * 16;             // kk=0
  const int cr1 = ((4 + (u >> 4)) ^ (u & 7)) * 16;       // kk=1

#define STG(base, R, kb, reg)                                                            \
  {                                                                                      \
    gl_lds16((base) + (size_t)((R) + srow) * 2048 + (kb) + scol, smem + (reg) + t * 16); \
    gl_lds16((base) + (size_t)((R) + 64 + srow) * 2048 + (kb) + scol,                    \
             smem + (reg) + 8192 + t * 16);                                              \
  }

#define LDA(buf, mi, cr) (*(const bf16x8*)(smem + (buf) + ard + arow + (mi) * 2048 + (cr)))
#define LDB(buf, ni, cr) (*(const bf16x8*)(smem + (buf) + brd + brow + (ni) * 2048 + (cr)))
#define MFMA(d, a_, b_) d = __builtin_amdgcn_mfma_f32_16x16x32_bf16(a_, b_, d, 0, 0, 0)
#define QUAD(MB, NB, B_0, B_1, B_2, B_3)                              \
  MFMA(acc[MB + 0][NB + 0], a00, B_0); MFMA(acc[MB + 0][NB + 0], a01, B_1); \
  MFMA(acc[MB + 0][NB + 1], a00, B_2); MFMA(acc[MB + 0][NB + 1], a01, B_3); \
  MFMA(acc[MB + 1][NB + 0], a10, B_0); MFMA(acc[MB + 1][NB + 0], a11, B_1); \
  MFMA(acc[MB + 1][NB + 1], a10, B_2); MFMA(acc[MB + 1][NB + 1], a11, B_3); \
  MFMA(acc[MB + 2][NB + 0], a20, B_0); MFMA(acc[MB + 2][NB + 0], a21, B_1); \
  MFMA(acc[MB + 2][NB + 1], a20, B_2); MFMA(acc[MB + 2][NB + 1], a21, B_3); \
  MFMA(acc[MB + 3][NB + 0], a30, B_0); MFMA(acc[MB + 3][NB + 0], a31, B_1); \
  MFMA(acc[MB + 3][NB + 1], a30, B_2); MFMA(acc[MB + 3][NB + 1], a31, B_3);

  f32x4 acc[8][4];
#pragma unroll
  for (int i = 0; i < 8; ++i)
#pragma unroll
    for (int j = 0; j < 4; ++j) acc[i][j] = (f32x4){0.f, 0.f, 0.f, 0.f};

  bf16x8 a00, a01, a10, a11, a20, a21, a30, a31;
  bf16x8 b00, b01, b10, b11, b20, b21, b30, b31;

  STG(Bsrc, 0, 0, 32768) STG(Bsrc, 128, 0, 49152)
  STG(Asrc, 0, 0, 0) STG(Asrc, 128, 0, 16384)
  STG(Bsrc, 0, 64, 65536 + 32768) STG(Bsrc, 128, 64, 65536 + 49152)
  asm volatile("s_waitcnt vmcnt(4)" ::: "memory");
  bar();

  for (int i = 0; i < 16; ++i) {
    const int kA1 = (2 * i + 1) * 64;
    const int kT2 = (2 * i + 2) * 64;
    const int kB3 = (2 * i + 3) * 64;
    // ---- P1 ----
    a00 = LDA(0, 0, cr0); a01 = LDA(0, 0, cr1); a10 = LDA(0, 1, cr0); a11 = LDA(0, 1, cr1);
    a20 = LDA(0, 2, cr0); a21 = LDA(0, 2, cr1); a30 = LDA(0, 3, cr0); a31 = LDA(0, 3, cr1);
    b00 = LDB(0, 0, cr0); b01 = LDB(0, 0, cr1); b10 = LDB(0, 1, cr0); b11 = LDB(0, 1, cr1);
    STG(Asrc, 0, kA1, 65536 + 0)
    bar();
    __builtin_amdgcn_s_setprio(1); QUAD(0, 0, b00, b01, b10, b11) __builtin_amdgcn_s_setprio(0);
    bar();
    // ---- P2 ----
    b20 = LDB(0, 2, cr0); b21 = LDB(0, 2, cr1); b30 = LDB(0, 3, cr0); b31 = LDB(0, 3, cr1);
    STG(Asrc, 128, kA1, 65536 + 16384)
    bar();
    __builtin_amdgcn_s_setprio(1); QUAD(0, 2, b20, b21, b30, b31) __builtin_amdgcn_s_setprio(0);
    bar();
    // ---- P3 ----
    a00 = LDA(0, 4, cr0); a01 = LDA(0, 4, cr1); a10 = LDA(0, 5, cr0); a11 = LDA(0, 5, cr1);
    a20 = LDA(0, 6, cr0); a21 = LDA(0, 6, cr1); a30 = LDA(0, 7, cr0); a31 = LDA(0, 7, cr1);
    if (i < 15) STG(Bsrc, 0, kT2, 32768)
    bar();
    __builtin_amdgcn_s_setprio(1); QUAD(4, 0, b00, b01, b10, b11) __builtin_amdgcn_s_setprio(0);
    bar();
    // ---- P4 ----
    if (i < 15) STG(Bsrc, 128, kT2, 49152)
    bar();
    __builtin_amdgcn_s_setprio(1); QUAD(4, 2, b20, b21, b30, b31) __builtin_amdgcn_s_setprio(0);
    if (i == 15) { asm volatile("s_waitcnt vmcnt(0)" ::: "memory"); }
    else         { asm volatile("s_waitcnt vmcnt(4)" ::: "memory"); }
    bar();
    // ---- P5 ----
    a00 = LDA(65536, 0, cr0); a01 = LDA(65536, 0, cr1); a10 = LDA(65536, 1, cr0); a11 = LDA(65536, 1, cr1);
    a20 = LDA(65536, 2, cr0); a21 = LDA(65536, 2, cr1); a30 = LDA(65536, 3, cr0); a31 = LDA(65536, 3, cr1);
    b00 = LDB(65536, 0, cr0); b01 = LDB(65536, 0, cr1); b10 = LDB(65536, 1, cr0); b11 = LDB(65536, 1, cr1);
    if (i < 15) STG(Asrc, 0, kT2, 0)
    bar();
    __builtin_amdgcn_s_setprio(1); QUAD(0, 0, b00, b01, b10, b11) __builtin_amdgcn_s_setprio(0);
    bar();
    // ---- P6 ----
    b20 = LDB(65536, 2, cr0); b21 = LDB(65536, 2, cr1); b30 = LDB(65536, 3, cr0); b31 = LDB(65536, 3, cr1);
    if (i < 15) STG(Asrc, 128, kT2, 16384)
    bar();
    __builtin_amdgcn_s_setprio(1); QUAD(0, 2, b20, b21, b30, b31) __builtin_amdgcn_s_setprio(0);
    bar();
    // ---- P7 ----
    a00 = LDA(65536, 4, cr0); a01 = LDA(65536, 4, cr1); a10 = LDA(65536, 5, cr0); a11 = LDA(65536, 5, cr1);
    a20 = LDA(65536, 6, cr0); a21 = LDA(65536, 6, cr1); a30 = LDA(65536, 7, cr0); a31 = LDA(65536, 7, cr1);
    if (i < 15) STG(Bsrc, 0, kB3, 65536 + 32768)
    bar();
    __builtin_amdgcn_s_setprio(1); QUAD(4, 0, b00, b01, b10, b11) __builtin_amdgcn_s_setprio(0);
    bar();
    // ---- P8 ----
    if (i < 15) STG(Bsrc, 128, kB3, 65536 + 49152)
    bar();
    __builtin_amdgcn_s_setprio(1); QUAD(4, 2, b20, b21, b30, b31) __builtin_amdgcn_s_setprio(0);
    asm volatile("s_waitcnt vmcnt(4)" ::: "memory");
    bar();
  }
#undef QUAD
#undef MFMA
#undef LDA
#undef LDB
#undef STG

  // epilogue (round-6 verified scatter): m = mbase+mi*16+(u>>4)*4+jj, n = nbase+ni*16+(u&15)
  const int mbase = mt * 256 + wm * 128;
  const int nbase = nt * 256 + wn * 64;
#pragma unroll
  for (int mi = 0; mi < 8; ++mi)
#pragma unroll
    for (int ni = 0; ni < 4; ++ni)
#pragma unroll
      for (int jj = 0; jj < 4; ++jj) {
        float v = acc[mi][ni][jj];
        int m = mbase + mi * 16 + ((u >> 4) << 2) + jj;
        int n = nbase + ni * 16 + (u & 15);
        if constexpr (MODE == 0) {  // Q
          ((u16*)Cb)[(size_t)m * 2048 + n] = f2bf(fmaxf(v, 0.f) * INV_SCALE);
        } else if constexpr (MODE == 1 || MODE == 2) {  // KT / VT per-head transposed
          float q = (MODE == 1) ? fmaxf(v, 0.f) * INV_SCALE : v;
          int bh = ((m >> 12) << 4) | (n >> 7);
          ((u16*)Cb)[(size_t)bh * 524288 + (size_t)(n & 127) * 4096 + (m & 4095)] = f2bf(q);
        } else if constexpr (MODE == 3) {  // U = silu
          float s = v * (1.f / (1.f + __expf(-v)));
          ((u16*)Cb)[(size_t)m * 2048 + n] = f2bf(s);
        } else {  // MODE 6: final fp32
          ((float*)Cb)[(size_t)m * 2048 + n] = v;
        }
      }
}

// ================= 128x128 KV-partial kernel =================
__global__ __launch_bounds__(256) void gemmKV(const u16* __restrict__ Ab,
                                              const u16* __restrict__ Bb,
                                              float* __restrict__ Cb) {
  __shared__ __align__(16) char smem[16384];

  const int t = threadIdx.x;
  const int u = t & 63;
  const int wid = t >> 6;
  const int wr = wid >> 1, wc = wid & 1;

  const u16* Au = Ab + (size_t)blockIdx.y * 524288 + blockIdx.x * 1024;
  const u16* Bu = Bb + (size_t)blockIdx.y * 524288 + blockIdx.x * 1024;

  const int srow = t >> 2;
  const int scolb = (t & 3) * 16;

  f32x4 acc[4][4];
#pragma unroll
  for (int i = 0; i < 4; ++i)
#pragma unroll
    for (int j = 0; j < 4; ++j) acc[i][j] = (f32x4){0.f, 0.f, 0.f, 0.f};

  const int aoff = (wr * 64 + (u & 15)) * 64 + (u >> 4) * 16;
  const int boff = 8192 + (wc * 64 + (u & 15)) * 64 + (u >> 4) * 16;

  for (int k0 = 0; k0 < 1024; k0 += 32) {
    const char* ga = (const char*)Au + ((size_t)srow * 4096 + k0) * 2 + scolb;
    const char* gb = (const char*)Bu + ((size_t)srow * 4096 + k0) * 2 + scolb;
    gl_lds16(ga, smem + t * 16);
    gl_lds16(ga + (size_t)64 * 4096 * 2, smem + 4096 + t * 16);
    gl_lds16(gb, smem + 8192 + t * 16);
    gl_lds16(gb + (size_t)64 * 4096 * 2, smem + 12288 + t * 16);
    __syncthreads();

    bf16x8 af[4], bfr[4];
#pragma unroll
    for (int mi = 0; mi < 4; ++mi) af[mi] = *(const bf16x8*)(smem + aoff + mi * 1024);
#pragma unroll
    for (int ni = 0; ni < 4; ++ni) bfr[ni] = *(const bf16x8*)(smem + boff + ni * 1024);
#pragma unroll
    for (int mi = 0; mi < 4; ++mi)
#pragma unroll
      for (int ni = 0; ni < 4; ++ni)
        acc[mi][ni] = __builtin_amdgcn_mfma_f32_16x16x32_bf16(af[mi], bfr[ni], acc[mi][ni], 0, 0, 0);
    __syncthreads();
  }

#pragma unroll
  for (int mi = 0; mi < 4; ++mi)
#pragma unroll
    for (int ni = 0; ni < 4; ++ni)
#pragma unroll
      for (int j = 0; j < 4; ++j) {
        int ml = wr * 64 + mi * 16 + ((u >> 4) << 2) + j;
        int nl = wc * 64 + ni * 16 + (u & 15);
        Cb[((size_t)blockIdx.x * 64 + blockIdx.y) * 16384 + ml * 128 + nl] = acc[mi][ni][j];
      }
}

// ---------------- KV partial reduce: 4 chunks fp32 -> bf16 ----------------
__global__ __launch_bounds__(256) void kv_reduce(const float* __restrict__ part,
                                                 u16* __restrict__ kvt) {
  int i = blockIdx.x * 256 + threadIdx.x;  // 64*128*128 = 1048576 elements
  float s = part[i] + part[i + 1048576] + part[i + 2097152] + part[i + 3145728];
  kvt[i] = f2bf(s);
}

// ======= gemmO: O = Q @ KVT^T per head, fused SRMS-norm * U epilogue =======
__global__ __launch_bounds__(256) void gemmO(const u16* __restrict__ Qb,
                                             const u16* __restrict__ KVT,
                                             const u16* __restrict__ Ub,
                                             u16* __restrict__ Ob) {
  __shared__ __align__(16) char smem[16384];
  __shared__ float ssb[2][128];

  const int t = threadIdx.x;
  const int u = t & 63;
  const int wid = t >> 6;
  const int wr = wid >> 1, wc = wid & 1;

  const int bh = blockIdx.y, b = bh >> 4, h = bh & 15;
  const int rowbase = b * 4096 + blockIdx.x * 128;
  const u16* Au = Qb + (size_t)rowbase * 2048 + h * 128;
  const u16* Bu = KVT + (size_t)bh * 16384;

  const int srow = t >> 2;
  const int scolb = (t & 3) * 16;

  f32x4 acc[4][4];
#pragma unroll
  for (int i = 0; i < 4; ++i)
#pragma unroll
    for (int j = 0; j < 4; ++j) acc[i][j] = (f32x4){0.f, 0.f, 0.f, 0.f};

  const int aoff = (wr * 64 + (u & 15)) * 64 + (u >> 4) * 16;
  const int boff = 8192 + (wc * 64 + (u & 15)) * 64 + (u >> 4) * 16;

  for (int k0 = 0; k0 < 128; k0 += 32) {
    const char* ga = (const char*)Au + ((size_t)srow * 2048 + k0) * 2 + scolb;
    const char* gb = (const char*)Bu + ((size_t)srow * 128 + k0) * 2 + scolb;
    gl_lds16(ga, smem + t * 16);
    gl_lds16(ga + (size_t)64 * 2048 * 2, smem + 4096 + t * 16);
    gl_lds16(gb, smem + 8192 + t * 16);
    gl_lds16(gb + (size_t)64 * 128 * 2, smem + 12288 + t * 16);
    __syncthreads();

    bf16x8 af[4], bfr[4];
#pragma unroll
    for (int mi = 0; mi < 4; ++mi) af[mi] = *(const bf16x8*)(smem + aoff + mi * 1024);
#pragma unroll
    for (int ni = 0; ni < 4; ++ni) bfr[ni] = *(const bf16x8*)(smem + boff + ni * 1024);
#pragma unroll
    for (int mi = 0; mi < 4; ++mi)
#pragma unroll
      for (int ni = 0; ni < 4; ++ni)
        acc[mi][ni] = __builtin_amdgcn_mfma_f32_16x16x32_bf16(af[mi], bfr[ni], acc[mi][ni], 0, 0, 0);
    __syncthreads();
  }

  // row ssq: reduce 4 ni + 16 lanes (u&15 group)
#pragma unroll
  for (int mi = 0; mi < 4; ++mi)
#pragma unroll
    for (int j = 0; j < 4; ++j) {
      float s = acc[mi][0][j] * acc[mi][0][j] + acc[mi][1][j] * acc[mi][1][j] +
                acc[mi][2][j] * acc[mi][2][j] + acc[mi][3][j] * acc[mi][3][j];
      s += __shfl_xor(s, 1); s += __shfl_xor(s, 2);
      s += __shfl_xor(s, 4); s += __shfl_xor(s, 8);
      if ((u & 15) == 0) ssb[wc][wr * 64 + mi * 16 + ((u >> 4) << 2) + j] = s;
    }
  __syncthreads();

#pragma unroll
  for (int mi = 0; mi < 4; ++mi)
#pragma unroll
    for (int j = 0; j < 4; ++j) {
      int ml = wr * 64 + mi * 16 + ((u >> 4) << 2) + j;
      float ss = ssb[0][ml] + ssb[1][ml];
      float inv = 1.0f / fmaxf(sqrtf(ss * (1.0f / 128.0f)), 1e-12f);
      size_t rb = (size_t)(rowbase + ml) * 2048 + h * 128;
#pragma unroll
      for (int ni = 0; ni < 4; ++ni) {
        int nl = wc * 64 + ni * 16 + (u & 15);
        float uval = bf2f(Ub[rb + nl]);
        Ob[rb + nl] = f2bf(acc[mi][ni][j] * inv * uval);
      }
    }
}

extern "C" void kernel_launch(void* const* d_in, const int* in_sizes, int n_in,
                              void* d_out, int out_size, void* d_ws, size_t ws_size,
                              hipStream_t stream) {
  (void)in_sizes; (void)n_in; (void)out_size; (void)ws_size;
  const float* x  = (const float*)d_in[0];
  const float* wq = (const float*)d_in[1];
  const float* wk = (const float*)d_in[2];
  const float* wv = (const float*)d_in[3];
  const float* wu = (const float*)d_in[4];
  const float* wo = (const float*)d_in[5];

  char* ws = (char*)d_ws;
  u16* wb   = (u16*)(ws + 0);             // 8 MiB, reused for each weight
  u16* xb   = (u16*)(ws + 8388608);       // 64 MiB (reused as Ob later)
  u16* Qb   = (u16*)(ws + 75497472);      // 64 MiB
  u16* Ub   = (u16*)(ws + 142606336);     // 64 MiB
  float* KVp = (float*)(ws + 209715200);  // 16 MiB: 4x64x128x128 fp32
  u16* KVT  = (u16*)(ws + 226492416);     // 2 MiB (end: 228,589,568 B)
  u16* Ob   = xb;                         // alias: xb dead after projections
  u16* KT   = (u16*)d_out;                // d_out scratch (first 64 MiB)
  u16* VT   = (u16*)d_out + 33554432;     // d_out scratch (second 64 MiB)

  // x -> bf16
  cvt_f32_bf16<<<4096, 256, 0, stream>>>((const float4*)x, xb, 8388608);

  // Q
  cvt_f32_bf16<<<4096, 256, 0, stream>>>((const float4*)wq, wb, 1048576);
  gemm256<0><<<512, 512, 0, stream>>>(xb, wb, Qb);
  // K -> KT
  cvt_f32_bf16<<<4096, 256, 0, stream>>>((const float4*)wk, wb, 1048576);
  gemm256<1><<<512, 512, 0, stream>>>(xb, wb, KT);
  // V -> VT
  cvt_f32_bf16<<<4096, 256, 0, stream>>>((const float4*)wv, wb, 1048576);
  gemm256<2><<<512, 512, 0, stream>>>(xb, wb, VT);
  // U
  cvt_f32_bf16<<<4096, 256, 0, stream>>>((const float4*)wu, wb, 1048576);
  gemm256<3><<<512, 512, 0, stream>>>(xb, wb, Ub);

  // KVT[bh][e][d] = sum_l VT[e][l] * KT[d][l]
  gemmKV<<<dim3(4, 64), 256, 0, stream>>>(VT, KT, KVp);
  kv_reduce<<<4096, 256, 0, stream>>>(KVp, KVT);

  // O = Q @ KVT^T per head, fused SRMS*U -> Ob (= xb). KT/VT dead after this.
  gemmO<<<dim3(32, 64), 256, 0, stream>>>(Qb, KVT, Ub, Ob);

  // out = Ob @ wo^T (fp32, full overwrite of d_out)
  cvt_f32_bf16<<<4096, 256, 0, stream>>>((const float4*)wo, wb, 1048576);
  gemm256<6><<<512, 512, 0, stream>>>(Ob, wb, (float*)d_out);
}

// Round 14
// 740.128 us; speedup vs baseline: 1.1528x; 1.0257x over previous
//
#include <hip/hip_runtime.h>
#include <hip/hip_bf16.h>

// MHRetention (B=4, L=4096, EMB=2048, H=16, hd=128), fp32 in/out, bf16 MFMA compute.
// Round-13: (1) QUAD reordered kk-major -> MFMA dep distance 8 (was 1); bitwise
// identical math. (2) Q+U and K+V projections merged into two N=4096 GEMMs
// (grid 1024, block-uniform region branch); weight cvts merged pairwise; KV
// partials in bf16 (ws high-water = 228,589,568 B, the proven bound).
// K-loop schedule otherwise byte-identical to the verified round-6/9/12 kernel.

typedef unsigned int u32;
typedef unsigned short u16;
typedef __bf16 bf16x8 __attribute__((ext_vector_type(8)));
typedef float f32x4 __attribute__((ext_vector_type(4)));

__device__ __forceinline__ u16 f2bf(float f) {
  u32 u = __float_as_uint(f);
  u = (u + 0x7fffu + ((u >> 16) & 1u)) >> 16;
  return (u16)u;
}
__device__ __forceinline__ float bf2f(u16 s) { return __uint_as_float(((u32)s) << 16); }

__device__ __forceinline__ void gl_lds16(const void* g, void* l) {
  __builtin_amdgcn_global_load_lds((const __attribute__((address_space(1))) void*)g,
                                   (__attribute__((address_space(3))) void*)l, 16, 0, 0);
}

__device__ __forceinline__ void bar() {
  asm volatile("" ::: "memory");
  __builtin_amdgcn_s_barrier();
  asm volatile("" ::: "memory");
}

#define INV_SCALE 0.08838834764831845f  // 1/sqrt(128)

// ---------------- fp32 -> bf16 conversion ----------------
__global__ __launch_bounds__(256) void cvt_f32_bf16(const float4* __restrict__ in,
                                                    u16* __restrict__ out, int n4) {
  int i = blockIdx.x * 256 + threadIdx.x;
  int stride = gridDim.x * 256;
  for (; i < n4; i += stride) {
    float4 v = in[i];
    u32 lo = (u32)f2bf(v.x) | ((u32)f2bf(v.y) << 16);
    u32 hi = (u32)f2bf(v.z) | ((u32)f2bf(v.w) << 16);
    ((uint2*)out)[i] = make_uint2(lo, hi);
  }
}

// two 2048x2048 fp32 weights -> one concatenated bf16 buffer [wA; wB]
__global__ __launch_bounds__(256) void cvt2_f32_bf16(const float4* __restrict__ a,
                                                     const float4* __restrict__ b,
                                                     u16* __restrict__ out) {
  int i = blockIdx.x * 256 + threadIdx.x;
  int stride = gridDim.x * 256;
  for (; i < 2097152; i += stride) {
    float4 v = (i < 1048576) ? a[i] : b[i - 1048576];
    u32 lo = (u32)f2bf(v.x) | ((u32)f2bf(v.y) << 16);
    u32 hi = (u32)f2bf(v.z) | ((u32)f2bf(v.w) << 16);
    ((uint2*)out)[i] = make_uint2(lo, hi);
  }
}

// ---- shared K-loop body (verified rounds 6..12; QUAD reordered kk-major) ----
#define GEMM_CORE_DECLS                                                                  \
  __shared__ __align__(16) char smem[131072];                                            \
  const int t = threadIdx.x;                                                             \
  const int u = t & 63;                                                                  \
  const int wid = t >> 6;                                                                \
  const int wm = wid >> 2;                                                               \
  const int wn = wid & 3;                                                                \
  const int srow = t >> 3;                                                               \
  const int scol = ((t & 7) ^ (srow & 7)) * 8;                                           \
  const int ard = wm * 16384;                                                            \
  const int brd = 32768 + (wn >> 1) * 16384;                                             \
  const int arow = (u & 15) * 128;                                                       \
  const int brow = ((wn & 1) * 64 + (u & 15)) * 128;                                     \
  const int cr0 = ((u >> 4) ^ (u & 7)) * 16;                                             \
  const int cr1 = ((4 + (u >> 4)) ^ (u & 7)) * 16;

#define STG(base, R, kb, reg)                                                            \
  {                                                                                      \
    gl_lds16((base) + (size_t)((R) + srow) * 2048 + (kb) + scol, smem + (reg) + t * 16); \
    gl_lds16((base) + (size_t)((R) + 64 + srow) * 2048 + (kb) + scol,                    \
             smem + (reg) + 8192 + t * 16);                                              \
  }

#define LDA(buf, mi, cr) (*(const bf16x8*)(smem + (buf) + ard + arow + (mi) * 2048 + (cr)))
#define LDB(buf, ni, cr) (*(const bf16x8*)(smem + (buf) + brd + brow + (ni) * 2048 + (cr)))
#define MFMA(d, a_, b_) d = __builtin_amdgcn_mfma_f32_16x16x32_bf16(a_, b_, d, 0, 0, 0)
// kk-major: 8 distinct accs for kk=0, then their kk=1 partners (dep distance 8).
// Per-acc order (kk0 then kk1) unchanged -> bitwise identical to prior rounds.
#define QUAD(MB, NB, B_0, B_1, B_2, B_3)                                    \
  MFMA(acc[MB + 0][NB + 0], a00, B_0); MFMA(acc[MB + 0][NB + 1], a00, B_2); \
  MFMA(acc[MB + 1][NB + 0], a10, B_0); MFMA(acc[MB + 1][NB + 1], a10, B_2); \
  MFMA(acc[MB + 2][NB + 0], a20, B_0); MFMA(acc[MB + 2][NB + 1], a20, B_2); \
  MFMA(acc[MB + 3][NB + 0], a30, B_0); MFMA(acc[MB + 3][NB + 1], a30, B_2); \
  MFMA(acc[MB + 0][NB + 0], a01, B_1); MFMA(acc[MB + 0][NB + 1], a01, B_3); \
  MFMA(acc[MB + 1][NB + 0], a11, B_1); MFMA(acc[MB + 1][NB + 1], a11, B_3); \
  MFMA(acc[MB + 2][NB + 0], a21, B_1); MFMA(acc[MB + 2][NB + 1], a21, B_3); \
  MFMA(acc[MB + 3][NB + 0], a31, B_1); MFMA(acc[MB + 3][NB + 1], a31, B_3);

#define GEMM_KLOOP(Asrc, Bsrc)                                                           \
  f32x4 acc[8][4];                                                                       \
  _Pragma("unroll") for (int i = 0; i < 8; ++i)                                          \
      _Pragma("unroll") for (int j = 0; j < 4; ++j) acc[i][j] = (f32x4){0.f, 0.f, 0.f, 0.f}; \
  bf16x8 a00, a01, a10, a11, a20, a21, a30, a31;                                         \
  bf16x8 b00, b01, b10, b11, b20, b21, b30, b31;                                         \
  STG(Bsrc, 0, 0, 32768) STG(Bsrc, 128, 0, 49152)                                        \
  STG(Asrc, 0, 0, 0) STG(Asrc, 128, 0, 16384)                                            \
  STG(Bsrc, 0, 64, 65536 + 32768) STG(Bsrc, 128, 64, 65536 + 49152)                      \
  asm volatile("s_waitcnt vmcnt(4)" ::: "memory");                                       \
  bar();                                                                                 \
  for (int i = 0; i < 16; ++i) {                                                         \
    const int kA1 = (2 * i + 1) * 64;                                                    \
    const int kT2 = (2 * i + 2) * 64;                                                    \
    const int kB3 = (2 * i + 3) * 64;                                                    \
    a00 = LDA(0, 0, cr0); a01 = LDA(0, 0, cr1); a10 = LDA(0, 1, cr0); a11 = LDA(0, 1, cr1); \
    a20 = LDA(0, 2, cr0); a21 = LDA(0, 2, cr1); a30 = LDA(0, 3, cr0); a31 = LDA(0, 3, cr1); \
    b00 = LDB(0, 0, cr0); b01 = LDB(0, 0, cr1); b10 = LDB(0, 1, cr0); b11 = LDB(0, 1, cr1); \
    STG(Asrc, 0, kA1, 65536 + 0)                                                         \
    bar();                                                                               \
    __builtin_amdgcn_s_setprio(1); QUAD(0, 0, b00, b01, b10, b11) __builtin_amdgcn_s_setprio(0); \
    bar();                                                                               \
    b20 = LDB(0, 2, cr0); b21 = LDB(0, 2, cr1); b30 = LDB(0, 3, cr0); b31 = LDB(0, 3, cr1); \
    STG(Asrc, 128, kA1, 65536 + 16384)                                                   \
    bar();                                                                               \
    __builtin_amdgcn_s_setprio(1); QUAD(0, 2, b20, b21, b30, b31) __builtin_amdgcn_s_setprio(0); \
    bar();                                                                               \
    a00 = LDA(0, 4, cr0); a01 = LDA(0, 4, cr1); a10 = LDA(0, 5, cr0); a11 = LDA(0, 5, cr1); \
    a20 = LDA(0, 6, cr0); a21 = LDA(0, 6, cr1); a30 = LDA(0, 7, cr0); a31 = LDA(0, 7, cr1); \
    if (i < 15) STG(Bsrc, 0, kT2, 32768)                                                 \
    bar();                                                                               \
    __builtin_amdgcn_s_setprio(1); QUAD(4, 0, b00, b01, b10, b11) __builtin_amdgcn_s_setprio(0); \
    bar();                                                                               \
    if (i < 15) STG(Bsrc, 128, kT2, 49152)                                               \
    bar();                                                                               \
    __builtin_amdgcn_s_setprio(1); QUAD(4, 2, b20, b21, b30, b31) __builtin_amdgcn_s_setprio(0); \
    if (i == 15) { asm volatile("s_waitcnt vmcnt(0)" ::: "memory"); }                    \
    else         { asm volatile("s_waitcnt vmcnt(4)" ::: "memory"); }                    \
    bar();                                                                               \
    a00 = LDA(65536, 0, cr0); a01 = LDA(65536, 0, cr1); a10 = LDA(65536, 1, cr0); a11 = LDA(65536, 1, cr1); \
    a20 = LDA(65536, 2, cr0); a21 = LDA(65536, 2, cr1); a30 = LDA(65536, 3, cr0); a31 = LDA(65536, 3, cr1); \
    b00 = LDB(65536, 0, cr0); b01 = LDB(65536, 0, cr1); b10 = LDB(65536, 1, cr0); b11 = LDB(65536, 1, cr1); \
    if (i < 15) STG(Asrc, 0, kT2, 0)                                                     \
    bar();                                                                               \
    __builtin_amdgcn_s_setprio(1); QUAD(0, 0, b00, b01, b10, b11) __builtin_amdgcn_s_setprio(0); \
    bar();                                                                               \
    b20 = LDB(65536, 2, cr0); b21 = LDB(65536, 2, cr1); b30 = LDB(65536, 3, cr0); b31 = LDB(65536, 3, cr1); \
    if (i < 15) STG(Asrc, 128, kT2, 16384)                                               \
    bar();                                                                               \
    __builtin_amdgcn_s_setprio(1); QUAD(0, 2, b20, b21, b30, b31) __builtin_amdgcn_s_setprio(0); \
    bar();                                                                               \
    a00 = LDA(65536, 4, cr0); a01 = LDA(65536, 4, cr1); a10 = LDA(65536, 5, cr0); a11 = LDA(65536, 5, cr1); \
    a20 = LDA(65536, 6, cr0); a21 = LDA(65536, 6, cr1); a30 = LDA(65536, 7, cr0); a31 = LDA(65536, 7, cr1); \
    if (i < 15) STG(Bsrc, 0, kB3, 65536 + 32768)                                         \
    bar();                                                                               \
    __builtin_amdgcn_s_setprio(1); QUAD(4, 0, b00, b01, b10, b11) __builtin_amdgcn_s_setprio(0); \
    bar();                                                                               \
    if (i < 15) STG(Bsrc, 128, kB3, 65536 + 49152)                                       \
    bar();                                                                               \
    __builtin_amdgcn_s_setprio(1); QUAD(4, 2, b20, b21, b30, b31) __builtin_amdgcn_s_setprio(0); \
    asm volatile("s_waitcnt vmcnt(4)" ::: "memory");                                     \
    bar();                                                                               \
  }

// ===== paired projection GEMM: A[16384][2048] x W2[4096][2048]^T =====
// PAIR 0: region0 -> Qb (relu/scale), region1 -> Ub (silu)
// PAIR 1: region0 -> KT (relu/scale, per-head transpose), region1 -> VT (transpose)
template <int PAIR>
__global__ __launch_bounds__(512, 2) void gemm256P(const u16* __restrict__ Ab,
                                                   const u16* __restrict__ Bb,
                                                   u16* __restrict__ C0,
                                                   u16* __restrict__ C1) {
  GEMM_CORE_DECLS
  const int wgid = blockIdx.x;                  // 1024 blocks
  const int swz = (wgid & 7) * 128 + (wgid >> 3);
  const int mt = swz >> 4;                      // 0..63
  const int nt = swz & 15;                      // 0..15
  const u16* Asrc = Ab + (size_t)mt * 256 * 2048;
  const u16* Bsrc = Bb + (size_t)nt * 256 * 2048;

  GEMM_KLOOP(Asrc, Bsrc)

  const int mbase = mt * 256 + wm * 128;
  const int nbase = nt * 256 + wn * 64;         // 0..4095
  const int reg = nt >> 3;                      // block-uniform region
  u16* Cr = reg ? C1 : C0;
#pragma unroll
  for (int mi = 0; mi < 8; ++mi)
#pragma unroll
    for (int ni = 0; ni < 4; ++ni)
#pragma unroll
      for (int jj = 0; jj < 4; ++jj) {
        float v = acc[mi][ni][jj];
        int m = mbase + mi * 16 + ((u >> 4) << 2) + jj;
        int n = (nbase + ni * 16 + (u & 15)) & 2047;  // col within region
        if constexpr (PAIR == 0) {
          float o = (reg == 0) ? fmaxf(v, 0.f) * INV_SCALE
                               : v * (1.f / (1.f + __expf(-v)));
          Cr[(size_t)m * 2048 + n] = f2bf(o);
        } else {
          float q = (reg == 0) ? fmaxf(v, 0.f) * INV_SCALE : v;
          int bh = ((m >> 12) << 4) | (n >> 7);
          Cr[(size_t)bh * 524288 + (size_t)(n & 127) * 4096 + (m & 4095)] = f2bf(q);
        }
      }
}

// ===== final GEMM: Ob[16384][2048] x wo[2048][2048]^T -> fp32 d_out =====
__global__ __launch_bounds__(512, 2) void gemm256F(const u16* __restrict__ Ab,
                                                   const u16* __restrict__ Bb,
                                                   float* __restrict__ Cb) {
  GEMM_CORE_DECLS
  const int wgid = blockIdx.x;                  // 512 blocks
  const int swz = (wgid & 7) * 64 + (wgid >> 3);
  const int mt = swz >> 3;                      // 0..63
  const int nt = swz & 7;                       // 0..7
  const u16* Asrc = Ab + (size_t)mt * 256 * 2048;
  const u16* Bsrc = Bb + (size_t)nt * 256 * 2048;

  GEMM_KLOOP(Asrc, Bsrc)

  const int mbase = mt * 256 + wm * 128;
  const int nbase = nt * 256 + wn * 64;
#pragma unroll
  for (int mi = 0; mi < 8; ++mi)
#pragma unroll
    for (int ni = 0; ni < 4; ++ni)
#pragma unroll
      for (int jj = 0; jj < 4; ++jj) {
        int m = mbase + mi * 16 + ((u >> 4) << 2) + jj;
        int n = nbase + ni * 16 + (u & 15);
        Cb[(size_t)m * 2048 + n] = acc[mi][ni][jj];
      }
}

// ================= 128x128 KV-partial kernel (bf16 partials) =================
__global__ __launch_bounds__(256) void gemmKV(const u16* __restrict__ Ab,
                                              const u16* __restrict__ Bb,
                                              u16* __restrict__ Cb) {
  __shared__ __align__(16) char smem[16384];

  const int t = threadIdx.x;
  const int u = t & 63;
  const int wid = t >> 6;
  const int wr = wid >> 1, wc = wid & 1;

  const u16* Au = Ab + (size_t)blockIdx.y * 524288 + blockIdx.x * 1024;
  const u16* Bu = Bb + (size_t)blockIdx.y * 524288 + blockIdx.x * 1024;

  const int srow = t >> 2;
  const int scolb = (t & 3) * 16;

  f32x4 acc[4][4];
#pragma unroll
  for (int i = 0; i < 4; ++i)
#pragma unroll
    for (int j = 0; j < 4; ++j) acc[i][j] = (f32x4){0.f, 0.f, 0.f, 0.f};

  const int aoff = (wr * 64 + (u & 15)) * 64 + (u >> 4) * 16;
  const int boff = 8192 + (wc * 64 + (u & 15)) * 64 + (u >> 4) * 16;

  for (int k0 = 0; k0 < 1024; k0 += 32) {
    const char* ga = (const char*)Au + ((size_t)srow * 4096 + k0) * 2 + scolb;
    const char* gb = (const char*)Bu + ((size_t)srow * 4096 + k0) * 2 + scolb;
    gl_lds16(ga, smem + t * 16);
    gl_lds16(ga + (size_t)64 * 4096 * 2, smem + 4096 + t * 16);
    gl_lds16(gb, smem + 8192 + t * 16);
    gl_lds16(gb + (size_t)64 * 4096 * 2, smem + 12288 + t * 16);
    __syncthreads();

    bf16x8 af[4], bfr[4];
#pragma unroll
    for (int mi = 0; mi < 4; ++mi) af[mi] = *(const bf16x8*)(smem + aoff + mi * 1024);
#pragma unroll
    for (int ni = 0; ni < 4; ++ni) bfr[ni] = *(const bf16x8*)(smem + boff + ni * 1024);
#pragma unroll
    for (int mi = 0; mi < 4; ++mi)
#pragma unroll
      for (int ni = 0; ni < 4; ++ni)
        acc[mi][ni] = __builtin_amdgcn_mfma_f32_16x16x32_bf16(af[mi], bfr[ni], acc[mi][ni], 0, 0, 0);
    __syncthreads();
  }

#pragma unroll
  for (int mi = 0; mi < 4; ++mi)
#pragma unroll
    for (int ni = 0; ni < 4; ++ni)
#pragma unroll
      for (int j = 0; j < 4; ++j) {
        int ml = wr * 64 + mi * 16 + ((u >> 4) << 2) + j;
        int nl = wc * 64 + ni * 16 + (u & 15);
        Cb[((size_t)blockIdx.x * 64 + blockIdx.y) * 16384 + ml * 128 + nl] = f2bf(acc[mi][ni][j]);
      }
}

// ---------------- KV partial reduce: 4 bf16 chunks -> bf16 ----------------
__global__ __launch_bounds__(256) void kv_reduce(const u16* __restrict__ part,
                                                 u16* __restrict__ kvt) {
  int i = blockIdx.x * 256 + threadIdx.x;  // 1048576 elements
  float s = bf2f(part[i]) + bf2f(part[i + 1048576]) + bf2f(part[i + 2097152]) +
            bf2f(part[i + 3145728]);
  kvt[i] = f2bf(s);
}

// ======= gemmO: O = Q @ KVT^T per head, fused SRMS-norm * U epilogue =======
__global__ __launch_bounds__(256) void gemmO(const u16* __restrict__ Qb,
                                             const u16* __restrict__ KVT,
                                             const u16* __restrict__ Ub,
                                             u16* __restrict__ Ob) {
  __shared__ __align__(16) char smem[16384];
  __shared__ float ssb[2][128];

  const int t = threadIdx.x;
  const int u = t & 63;
  const int wid = t >> 6;
  const int wr = wid >> 1, wc = wid & 1;

  const int bh = blockIdx.y, b = bh >> 4, h = bh & 15;
  const int rowbase = b * 4096 + blockIdx.x * 128;
  const u16* Au = Qb + (size_t)rowbase * 2048 + h * 128;
  const u16* Bu = KVT + (size_t)bh * 16384;

  const int srow = t >> 2;
  const int scolb = (t & 3) * 16;

  f32x4 acc[4][4];
#pragma unroll
  for (int i = 0; i < 4; ++i)
#pragma unroll
    for (int j = 0; j < 4; ++j) acc[i][j] = (f32x4){0.f, 0.f, 0.f, 0.f};

  const int aoff = (wr * 64 + (u & 15)) * 64 + (u >> 4) * 16;
  const int boff = 8192 + (wc * 64 + (u & 15)) * 64 + (u >> 4) * 16;

  for (int k0 = 0; k0 < 128; k0 += 32) {
    const char* ga = (const char*)Au + ((size_t)srow * 2048 + k0) * 2 + scolb;
    const char* gb = (const char*)Bu + ((size_t)srow * 128 + k0) * 2 + scolb;
    gl_lds16(ga, smem + t * 16);
    gl_lds16(ga + (size_t)64 * 2048 * 2, smem + 4096 + t * 16);
    gl_lds16(gb, smem + 8192 + t * 16);
    gl_lds16(gb + (size_t)64 * 128 * 2, smem + 12288 + t * 16);
    __syncthreads();

    bf16x8 af[4], bfr[4];
#pragma unroll
    for (int mi = 0; mi < 4; ++mi) af[mi] = *(const bf16x8*)(smem + aoff + mi * 1024);
#pragma unroll
    for (int ni = 0; ni < 4; ++ni) bfr[ni] = *(const bf16x8*)(smem + boff + ni * 1024);
#pragma unroll
    for (int mi = 0; mi < 4; ++mi)
#pragma unroll
      for (int ni = 0; ni < 4; ++ni)
        acc[mi][ni] = __builtin_amdgcn_mfma_f32_16x16x32_bf16(af[mi], bfr[ni], acc[mi][ni], 0, 0, 0);
    __syncthreads();
  }

#pragma unroll
  for (int mi = 0; mi < 4; ++mi)
#pragma unroll
    for (int j = 0; j < 4; ++j) {
      float s = acc[mi][0][j] * acc[mi][0][j] + acc[mi][1][j] * acc[mi][1][j] +
                acc[mi][2][j] * acc[mi][2][j] + acc[mi][3][j] * acc[mi][3][j];
      s += __shfl_xor(s, 1); s += __shfl_xor(s, 2);
      s += __shfl_xor(s, 4); s += __shfl_xor(s, 8);
      if ((u & 15) == 0) ssb[wc][wr * 64 + mi * 16 + ((u >> 4) << 2) + j] = s;
    }
  __syncthreads();

#pragma unroll
  for (int mi = 0; mi < 4; ++mi)
#pragma unroll
    for (int j = 0; j < 4; ++j) {
      int ml = wr * 64 + mi * 16 + ((u >> 4) << 2) + j;
      float ss = ssb[0][ml] + ssb[1][ml];
      float inv = 1.0f / fmaxf(sqrtf(ss * (1.0f / 128.0f)), 1e-12f);
      size_t rb = (size_t)(rowbase + ml) * 2048 + h * 128;
#pragma unroll
      for (int ni = 0; ni < 4; ++ni) {
        int nl = wc * 64 + ni * 16 + (u & 15);
        float uval = bf2f(Ub[rb + nl]);
        Ob[rb + nl] = f2bf(acc[mi][ni][j] * inv * uval);
      }
    }
}

extern "C" void kernel_launch(void* const* d_in, const int* in_sizes, int n_in,
                              void* d_out, int out_size, void* d_ws, size_t ws_size,
                              hipStream_t stream) {
  (void)in_sizes; (void)n_in; (void)out_size; (void)ws_size;
  const float* x  = (const float*)d_in[0];
  const float* wq = (const float*)d_in[1];
  const float* wk = (const float*)d_in[2];
  const float* wv = (const float*)d_in[3];
  const float* wu = (const float*)d_in[4];
  const float* wo = (const float*)d_in[5];

  char* ws = (char*)d_ws;
  u16* wb2   = (u16*)(ws + 0);            // 16 MiB (two weights, reused per stage)
  u16* xb    = (u16*)(ws + 16777216);     // 64 MiB (reused as Ob later)
  u16* Qb    = (u16*)(ws + 83886080);     // 64 MiB
  u16* Ub    = (u16*)(ws + 150994944);    // 64 MiB
  u16* KVp   = (u16*)(ws + 218103808);    // 8 MiB: 4x64x128x128 bf16 partials
  u16* KVT   = (u16*)(ws + 226492416);    // 2 MiB (end: 228,589,568 B — proven bound)
  u16* Ob    = xb;
  u16* KT    = (u16*)d_out;               // d_out scratch (first 64 MiB)
  u16* VT    = (u16*)d_out + 33554432;    // d_out scratch (second 64 MiB)

  // x -> bf16
  cvt_f32_bf16<<<4096, 256, 0, stream>>>((const float4*)x, xb, 8388608);

  // Q + U merged (N=4096)
  cvt2_f32_bf16<<<4096, 256, 0, stream>>>((const float4*)wq, (const float4*)wu, wb2);
  gemm256P<0><<<1024, 512, 0, stream>>>(xb, wb2, Qb, Ub);

  // K + V merged (N=4096), per-head transposed into d_out
  cvt2_f32_bf16<<<4096, 256, 0, stream>>>((const float4*)wk, (const float4*)wv, wb2);
  gemm256P<1><<<1024, 512, 0, stream>>>(xb, wb2, KT, VT);

  // KVT[bh][e][d] = sum_l VT[e][l] * KT[d][l]  (bf16 partials -> fp32 reduce)
  gemmKV<<<dim3(4, 64), 256, 0, stream>>>(VT, KT, KVp);
  kv_reduce<<<4096, 256, 0, stream>>>(KVp, KVT);

  // O = Q @ KVT^T per head, fused SRMS*U -> Ob (= xb). KT/VT dead after this.
  gemmO<<<dim3(32, 64), 256, 0, stream>>>(Qb, KVT, Ub, Ob);

  // out = Ob @ wo^T (fp32, full overwrite of d_out)
  cvt_f32_bf16<<<4096, 256, 0, stream>>>((const float4*)wo, wb2, 1048576);
  gemm256F<<<512, 512, 0, stream>>>(Ob, wb2, (float*)d_out);
}